// Round 10
// baseline (75.549 us; speedup 1.0000x reference)
//
#include <hip/hip_runtime.h>
#include <cstdint>
#include <cstddef>

// ContrastiveLoss: B=8192, D=256 fp32 inputs.
// loss = mean_b [ log( exp(2*pos_b) + sum_c exp(2*z_i[b].z_k[c]) ) - 2*pos_b ]
// R9: m201-template port. 8 waves (2Mx4N), block tile 256 rows x (NT*256)
// cols streamed as 32 K-steps (K32 x col-tile). LDS ring-4 of
// {A 256x32, B 256x32} bricks (verified swizzle), stage depth 3,
// vmcnt(8) once/step, 2 phases/step each {ds_read || stage -> barrier ->
// lgkmcnt(0) -> setprio 16-MFMA -> barrier}. exp fused per col-tile.

constexpr int   D_DIM = 256;
constexpr float INV_T = 2.0f;   // 1/T, T=0.5

constexpr int NT = 4;           // col-tiles per block (each 256 cols)

typedef __attribute__((ext_vector_type(8))) short  bf16x8;
typedef __attribute__((ext_vector_type(4))) float  f32x4;

__device__ __forceinline__ unsigned short f32_to_bf16(float f) {
    unsigned int u = __float_as_uint(f);
    u += 0x7FFFu + ((u >> 16) & 1u);          // RNE
    return (unsigned short)(u >> 16);
}

__device__ __forceinline__ void gload_lds16(const void* g, void* l) {
    auto gp = reinterpret_cast<const __attribute__((address_space(1))) unsigned int*>(
        reinterpret_cast<uintptr_t>(g));
    auto lp = reinterpret_cast<__attribute__((address_space(3))) unsigned int*>(
        reinterpret_cast<uintptr_t>(l));
    __builtin_amdgcn_global_load_lds(gp, lp, 16, 0, 0);
}

// ---------------------------------------------------------------------------
// Kernel 1: per-row norms; write bf16 2*z_i (scaled) and z_k; fp32 pos_logit;
// zero rowsum. One 64-lane wave per row.
// ---------------------------------------------------------------------------
__global__ __launch_bounds__(256) void prep_kernel(
    const float* __restrict__ ei, const float* __restrict__ ej,
    const float* __restrict__ ek,
    unsigned short* __restrict__ zi, unsigned short* __restrict__ zk,
    float* __restrict__ pos_logit, float* __restrict__ rowsum, int B)
{
    const int w    = (int)((blockIdx.x * blockDim.x + threadIdx.x) >> 6);
    const int lane = (int)(threadIdx.x & 63);
    if (w >= B) return;

    const float4 vi = ((const float4*)(ei + (size_t)w * D_DIM))[lane];
    const float4 vj = ((const float4*)(ej + (size_t)w * D_DIM))[lane];
    const float4 vk = ((const float4*)(ek + (size_t)w * D_DIM))[lane];

    float ssi = vi.x*vi.x + vi.y*vi.y + vi.z*vi.z + vi.w*vi.w;
    float ssj = vj.x*vj.x + vj.y*vj.y + vj.z*vj.z + vj.w*vj.w;
    float ssk = vk.x*vk.x + vk.y*vk.y + vk.z*vk.z + vk.w*vk.w;
    float dij = vi.x*vj.x + vi.y*vj.y + vi.z*vj.z + vi.w*vj.w;

    #pragma unroll
    for (int off = 32; off; off >>= 1) {
        ssi += __shfl_xor(ssi, off);
        ssj += __shfl_xor(ssj, off);
        ssk += __shfl_xor(ssk, off);
        dij += __shfl_xor(dij, off);
    }
    const float ri = INV_T / fmaxf(sqrtf(ssi), 1e-12f);   // fold 1/T into z_i
    const float rj = 1.0f  / fmaxf(sqrtf(ssj), 1e-12f);
    const float rk = 1.0f  / fmaxf(sqrtf(ssk), 1e-12f);

    ushort4 oi, ok;
    oi.x = f32_to_bf16(vi.x * ri); oi.y = f32_to_bf16(vi.y * ri);
    oi.z = f32_to_bf16(vi.z * ri); oi.w = f32_to_bf16(vi.w * ri);
    ok.x = f32_to_bf16(vk.x * rk); ok.y = f32_to_bf16(vk.y * rk);
    ok.z = f32_to_bf16(vk.z * rk); ok.w = f32_to_bf16(vk.w * rk);
    ((ushort4*)(zi + (size_t)w * D_DIM))[lane] = oi;
    ((ushort4*)(zk + (size_t)w * D_DIM))[lane] = ok;

    if (lane == 0) {
        pos_logit[w] = dij * ri * rj;   // ri already includes 1/T
        rowsum[w]    = 0.0f;
    }
}

// ---------------------------------------------------------------------------
// Kernel 2: rows [by*256,+256) x cols [bx*(NT*256),+NT*256) of exp-sum of
// (2*Z_i).Z_k^T.   8 waves: wr = w>>2 (row half), wc = w&3 (col quarter);
// wave tile 128x64 = 8mi x 4ni frags of 16x16x32 bf16.
// K-stream: step s = ct*8 + k32 (ct = col-tile, k32 = K chunk).
// LDS: lds[slot 0..3][op A/B][rg 0..15][brick 512] — brick = [16 rows][32 k]
// with verified XOR swizzle (conflicts=0). Stage: wave w stages rg w*2,w*2+1
// of A (phase A) and B (phase B) for step s+3 -> 4 gload_lds/wave/step.
// ---------------------------------------------------------------------------
__global__ __launch_bounds__(512, 2) void sim_mfma_kernel(
    const unsigned short* __restrict__ zi, const unsigned short* __restrict__ zk,
    float* __restrict__ rowsum)
{
    __shared__ unsigned short lds[4][2][16][512];   // 128 KB

    const int t  = (int)threadIdx.x;
    const int w  = t >> 6;        // wave 0..7
    const int l  = t & 63;
    const int wr = w >> 2;        // row half (0..1)
    const int wc = w & 3;         // col quarter (0..3)
    const int rowBase = (int)blockIdx.y * 256;
    const int colBase = (int)blockIdx.x * (NT * 256);

    // ---- staging source (per-lane constants; verified swizzle) ----
    const int csrc = 8 * ((l & 3) ^ ((l >> 3) & 3));
    const int srow = l >> 2;      // row within 16-row brick
    const unsigned short* gA0 =
        zi + (size_t)(rowBase + (w * 2 + 0) * 16 + srow) * D_DIM + csrc;
    const unsigned short* gA1 =
        zi + (size_t)(rowBase + (w * 2 + 1) * 16 + srow) * D_DIM + csrc;
    const unsigned short* gB0 =
        zk + (size_t)(colBase + (w * 2 + 0) * 16 + srow) * D_DIM + csrc;
    const unsigned short* gB1 =
        zk + (size_t)(colBase + (w * 2 + 1) * 16 + srow) * D_DIM + csrc;

    #define STAGE_A(slot, s) {                                               \
        const int k_ = ((s) & 7) * 32;                                       \
        gload_lds16(gA0 + k_, &lds[slot][0][w * 2 + 0][0]);                  \
        gload_lds16(gA1 + k_, &lds[slot][0][w * 2 + 1][0]);                  \
    }
    #define STAGE_B(slot, s) {                                               \
        const size_t o_ = (size_t)((s) >> 3) * (256 * D_DIM)                 \
                        + (size_t)(((s) & 7) * 32);                          \
        gload_lds16(gB0 + o_, &lds[slot][1][w * 2 + 0][0]);                  \
        gload_lds16(gB1 + o_, &lds[slot][1][w * 2 + 1][0]);                  \
    }

    // ---- fragment read offset within a brick (verified swizzle) ----
    const int rA = l & 15;
    const int ce = rA * 32 + 8 * ((l >> 4) ^ ((rA >> 1) & 3));
    #define AFRAG(slot, mi) (*(const bf16x8*)&lds[slot][0][wr * 8 + (mi)][ce])
    #define BFRAG(slot, ni) (*(const bf16x8*)&lds[slot][1][wc * 4 + (ni)][ce])

    // ---- prologue: stage steps 0,1,2 (12 loads); gate step 0 ----
    STAGE_A(0, 0); STAGE_B(0, 0);
    STAGE_A(1, 1); STAGE_B(1, 1);
    STAGE_A(2, 2); STAGE_B(2, 2);
    asm volatile("s_waitcnt vmcnt(8)" ::: "memory");   // step-0 loads landed
    __builtin_amdgcn_s_barrier();

    float partAcc[8][4] = {};

    for (int ct = 0; ct < NT; ++ct) {
        f32x4 acc[8][4] = {};

        #pragma unroll
        for (int k8 = 0; k8 < 8; ++k8) {
            const int s    = ct * 8 + k8;
            int       s3   = s + 3;
            if (s3 > NT * 8 - 1) s3 = NT * 8 - 1;   // tail: dup-stage last
            const int slot = k8 & 3;                 // compile-time
            const int sst  = (k8 + 3) & 3;           // compile-time

            // ================= phase A =================
            bf16x8 af[8], bf0, bf1;
            #pragma unroll
            for (int mi = 0; mi < 8; ++mi) af[mi] = AFRAG(slot, mi);
            bf0 = BFRAG(slot, 0);
            bf1 = BFRAG(slot, 1);
            STAGE_A(sst, s3);
            __builtin_amdgcn_s_barrier();
            asm volatile("s_waitcnt lgkmcnt(0)" ::: "memory");
            __builtin_amdgcn_sched_barrier(0);       // rule 18
            __builtin_amdgcn_s_setprio(1);
            #pragma unroll
            for (int mi = 0; mi < 8; ++mi) {
                acc[mi][0] = __builtin_amdgcn_mfma_f32_16x16x32_bf16(
                    af[mi], bf0, acc[mi][0], 0, 0, 0);
                acc[mi][1] = __builtin_amdgcn_mfma_f32_16x16x32_bf16(
                    af[mi], bf1, acc[mi][1], 0, 0, 0);
            }
            __builtin_amdgcn_s_setprio(0);
            __builtin_amdgcn_sched_barrier(0);
            __builtin_amdgcn_s_barrier();

            // ================= phase B =================
            bf16x8 bf2 = BFRAG(slot, 2);
            bf16x8 bf3 = BFRAG(slot, 3);
            STAGE_B(sst, s3);
            // gate step s+1 (outstanding after wait: s+2, s+3 = 8 loads)
            asm volatile("s_waitcnt vmcnt(8)" ::: "memory");
            __builtin_amdgcn_s_barrier();
            asm volatile("s_waitcnt lgkmcnt(0)" ::: "memory");
            __builtin_amdgcn_sched_barrier(0);       // rule 18
            __builtin_amdgcn_s_setprio(1);
            #pragma unroll
            for (int mi = 0; mi < 8; ++mi) {
                acc[mi][2] = __builtin_amdgcn_mfma_f32_16x16x32_bf16(
                    af[mi], bf2, acc[mi][2], 0, 0, 0);
                acc[mi][3] = __builtin_amdgcn_mfma_f32_16x16x32_bf16(
                    af[mi], bf3, acc[mi][3], 0, 0, 0);
            }
            __builtin_amdgcn_s_setprio(0);
            __builtin_amdgcn_sched_barrier(0);
            __builtin_amdgcn_s_barrier();
        }

        // per-col-tile epilogue: exp + in-lane partial sums (A pre-scaled)
        #pragma unroll
        for (int mi = 0; mi < 8; ++mi)
            #pragma unroll
            for (int r = 0; r < 4; ++r) {
                float sum = 0.f;
                #pragma unroll
                for (int ni = 0; ni < 4; ++ni)
                    sum += __expf(acc[mi][ni][r]);
                partAcc[mi][r] += sum;
            }
    }
    #undef STAGE_A
    #undef STAGE_B
    #undef AFRAG
    #undef BFRAG

    // block epilogue: reduce across the 16 column-lanes, one atomic set
    #pragma unroll
    for (int off = 1; off <= 8; off <<= 1)
        #pragma unroll
        for (int mi = 0; mi < 8; ++mi)
            #pragma unroll
            for (int r = 0; r < 4; ++r)
                partAcc[mi][r] += __shfl_xor(partAcc[mi][r], off);

    if ((l & 15) == 0) {
        const int rg4 = (l >> 4) * 4;    // C/D layout: row = (l>>4)*4 + reg
        #pragma unroll
        for (int mi = 0; mi < 8; ++mi)
            #pragma unroll
            for (int r = 0; r < 4; ++r)
                atomicAdd(&rowsum[rowBase + wr * 128 + mi * 16 + rg4 + r],
                          partAcc[mi][r]);
    }
}

// ---------------------------------------------------------------------------
// Kernel 3: loss = mean_b [ log(exp(pos_b) + rowsum_b) - pos_b ]
// ---------------------------------------------------------------------------
__global__ __launch_bounds__(1024) void finalize_kernel(
    const float* __restrict__ pos_logit, const float* __restrict__ rowsum,
    float* __restrict__ out, int B)
{
    __shared__ float red[1024];
    float acc = 0.f;
    for (int b = (int)threadIdx.x; b < B; b += 1024) {
        const float pl = pos_logit[b];
        acc += logf(expf(pl) + rowsum[b]) - pl;
    }
    red[threadIdx.x] = acc;
    __syncthreads();
    #pragma unroll
    for (int s = 512; s; s >>= 1) {
        if ((int)threadIdx.x < s) red[threadIdx.x] += red[threadIdx.x + s];
        __syncthreads();
    }
    if (threadIdx.x == 0) out[0] = red[0] / (float)B;
}

// ---------------------------------------------------------------------------
extern "C" void kernel_launch(void* const* d_in, const int* in_sizes, int n_in,
                              void* d_out, int out_size, void* d_ws, size_t ws_size,
                              hipStream_t stream)
{
    const float* ei = (const float*)d_in[0];
    const float* ej = (const float*)d_in[1];
    const float* ek = (const float*)d_in[2];
    const int B = in_sizes[0] / D_DIM;   // 8192

    unsigned short* zi = (unsigned short*)d_ws;
    unsigned short* zk = zi + (size_t)B * D_DIM;
    float* rowsum      = (float*)(zk + (size_t)B * D_DIM);
    float* pos_logit   = rowsum + B;

    prep_kernel<<<dim3((B + 3) / 4), dim3(256), 0, stream>>>(
        ei, ej, ek, zi, zk, pos_logit, rowsum, B);

    dim3 grid(B / (NT * 256), B / 256);   // (8, 32) = 256 blocks = 1/CU
    sim_mfma_kernel<<<grid, dim3(512), 0, stream>>>(zi, zk, rowsum);

    finalize_kernel<<<dim3(1), dim3(1024), 0, stream>>>(
        pos_logit, rowsum, (float*)d_out, B);
}

// Round 11
// 52.720 us; speedup vs baseline: 1.4330x; 1.4330x over previous
//
#include <hip/hip_runtime.h>
#include <cstdint>
#include <cstddef>

// ContrastiveLoss: B=8192, D=256 fp32 inputs.
// loss = mean_b [ log( exp(2*pos_b) + sum_c exp(2*z_i[b].z_k[c]) ) - 2*pos_b ]
// R10: barrier-free MFMA GEMM over fragment-PACKED operands.
//   prep: normalize, scale z_i by 2, write both matrices in MFMA fragment
//         order: frag f = (rowgroup g, kt) -> 1 KB contiguous, lane l owns
//         bytes [l*16,+16)  (row = g*16 + (l&15), k = kt*32 + (l>>4)*8).
//   sim:  A panel (64 frags, 64 KB, contiguous in packed layout) staged to
//         LDS ONCE via linear global_load_lds; ONE barrier; then 64 K-steps
//         free-running: 4 ds_read_b128 (A) + 4 global dwordx4 (B, L2-hot),
//         double-buffered 2 steps ahead; 16 MFMA per step; NO barriers.
// exp fused per tile; shuffle-reduce + atomics once per block.

constexpr int   D_DIM = 256;
constexpr float INV_T = 2.0f;   // 1/T, T=0.5

constexpr int BM = 128;         // block rows
constexpr int BN = 128;         // cols per tile
constexpr int NT = 8;           // column tiles per block (block = 128 x 1024)

typedef __attribute__((ext_vector_type(8))) short  bf16x8;
typedef __attribute__((ext_vector_type(4))) float  f32x4;

__device__ __forceinline__ unsigned short f32_to_bf16(float f) {
    unsigned int u = __float_as_uint(f);
    u += 0x7FFFu + ((u >> 16) & 1u);          // RNE
    return (unsigned short)(u >> 16);
}

__device__ __forceinline__ void gload_lds16(const void* g, void* l) {
    auto gp = reinterpret_cast<const __attribute__((address_space(1))) unsigned int*>(
        reinterpret_cast<uintptr_t>(g));
    auto lp = reinterpret_cast<__attribute__((address_space(3))) unsigned int*>(
        reinterpret_cast<uintptr_t>(l));
    __builtin_amdgcn_global_load_lds(gp, lp, 16, 0, 0);
}

// ---------------------------------------------------------------------------
// Kernel 1: per-16-row group: norms, pos_logit, rowsum init, PACKED bf16 out.
// Thread t: row_local = t>>4, chunk c = t&15 (16 elems). (verified R8)
// ---------------------------------------------------------------------------
__global__ __launch_bounds__(256) void prep_kernel(
    const float* __restrict__ ei, const float* __restrict__ ej,
    const float* __restrict__ ek,
    unsigned short* __restrict__ zip, unsigned short* __restrict__ zkp,
    float* __restrict__ pos_logit, float* __restrict__ rowsum)
{
    const int t  = (int)threadIdx.x;
    const int rl = t >> 4;              // row within group (0..15)
    const int c  = t & 15;              // 16-elem chunk (0..15)
    const int g  = (int)blockIdx.x;     // row group
    const int row = g * 16 + rl;

    const float4* pi = (const float4*)(ei + (size_t)row * D_DIM + c * 16);
    const float4* pj = (const float4*)(ej + (size_t)row * D_DIM + c * 16);
    const float4* pk = (const float4*)(ek + (size_t)row * D_DIM + c * 16);
    float4 vi[4], vj[4], vk[4];
    #pragma unroll
    for (int q = 0; q < 4; ++q) { vi[q] = pi[q]; vj[q] = pj[q]; vk[q] = pk[q]; }

    float ssi = 0.f, ssj = 0.f, ssk = 0.f, dij = 0.f;
    #pragma unroll
    for (int q = 0; q < 4; ++q) {
        ssi += vi[q].x*vi[q].x + vi[q].y*vi[q].y + vi[q].z*vi[q].z + vi[q].w*vi[q].w;
        ssj += vj[q].x*vj[q].x + vj[q].y*vj[q].y + vj[q].z*vj[q].z + vj[q].w*vj[q].w;
        ssk += vk[q].x*vk[q].x + vk[q].y*vk[q].y + vk[q].z*vk[q].z + vk[q].w*vk[q].w;
        dij += vi[q].x*vj[q].x + vi[q].y*vj[q].y + vi[q].z*vj[q].z + vi[q].w*vj[q].w;
    }
    #pragma unroll
    for (int off = 1; off <= 8; off <<= 1) {    // reduce over the 16 c-lanes
        ssi += __shfl_xor(ssi, off);
        ssj += __shfl_xor(ssj, off);
        ssk += __shfl_xor(ssk, off);
        dij += __shfl_xor(dij, off);
    }
    const float ri = INV_T / fmaxf(sqrtf(ssi), 1e-12f);   // fold 1/T into z_i
    const float rj = 1.0f  / fmaxf(sqrtf(ssj), 1e-12f);
    const float rk = 1.0f  / fmaxf(sqrtf(ssk), 1e-12f);

    // pack: this thread's 16 elems are k in [c*16, c*16+16):
    //   kt = c>>1; first 8 -> ksub = 2*(c&1), second 8 -> ksub+1.
    bf16x8 hi0, hi1, hk0, hk1;
    #pragma unroll
    for (int q = 0; q < 4; ++q) {
        const float* fi = &vi[q].x;
        const float* fk = &vk[q].x;
        #pragma unroll
        for (int e = 0; e < 4; ++e) {
            const int idx = q * 4 + e;          // 0..15
            const unsigned short bi = f32_to_bf16(fi[e] * ri);
            const unsigned short bk = f32_to_bf16(fk[e] * rk);
            if (idx < 8) { hi0[idx] = (short)bi; hk0[idx] = (short)bk; }
            else         { hi1[idx - 8] = (short)bi; hk1[idx - 8] = (short)bk; }
        }
    }
    const int kt    = c >> 1;
    const int lane0 = rl + 16 * ((c & 1) * 2);
    const size_t fb = ((size_t)g * 8 + kt) * 512;    // frag base (elems)
    *(bf16x8*)(zip + fb + (size_t)lane0 * 8)        = hi0;
    *(bf16x8*)(zip + fb + (size_t)(lane0 + 16) * 8) = hi1;
    *(bf16x8*)(zkp + fb + (size_t)lane0 * 8)        = hk0;
    *(bf16x8*)(zkp + fb + (size_t)(lane0 + 16) * 8) = hk1;

    if (c == 0) {
        pos_logit[row] = dij * ri * rj;   // ri already includes 1/T
        rowsum[row]    = 0.0f;
    }
}

// ---------------------------------------------------------------------------
// Kernel 2: rows [by*128,+128) x cols [bx*1024,+1024) of exp-sum of
// (2*Z_i).Z_k^T. 4 waves (2x2), wave tile 64x64 = 4x4 frags of 16x16x32.
// A panel: 64 packed frags = 64 KB CONTIGUOUS -> staged to LDS once
// (16 linear gload_lds per wave), one barrier, then NO barriers.
// Per step: 4 ds_read_b128 (A frags) + 4 global dwordx4 (B frags),
// double-buffered 2 steps ahead; 16 MFMA. Waves free-run.
// ---------------------------------------------------------------------------
__global__ __launch_bounds__(256, 2) void sim_mfma_kernel(
    const unsigned short* __restrict__ zip, const unsigned short* __restrict__ zkp,
    float* __restrict__ rowsum)
{
    __shared__ unsigned short Alds[64][512];   // 64 frags x 1 KB = 64 KB

    const int t  = (int)threadIdx.x;
    const int w  = t >> 6;        // wave 0..3
    const int l  = t & 63;
    const int wr = w >> 1;        // wave row (0..1)
    const int wc = w & 1;         // wave col (0..1)
    const int rowBase = (int)blockIdx.y * BM;

    // ---- prologue: stage A panel (contiguous 64 KB in packed layout) ----
    // frag indices [by*64, +64); wave w stages frags [w*16, +16).
    const unsigned short* Apanel = zip + ((size_t)blockIdx.y * 64) * 512;
    #pragma unroll
    for (int f = 0; f < 16; ++f)
        gload_lds16(Apanel + (((size_t)(w * 16 + f)) << 9) + (size_t)l * 8,
                    &Alds[w * 16 + f][0]);
    asm volatile("s_waitcnt vmcnt(0)" ::: "memory");
    __builtin_amdgcn_s_barrier();      // the ONLY barrier

    // ---- A frag read (LDS): frag (mi,kt) at Alds[(wr*4+mi)*8 + kt], +l*8
    #define LDA(dst, s_) {                                                    \
        const int kt_ = (s_) & 7;                                             \
        _Pragma("unroll")                                                     \
        for (int mi = 0; mi < 4; ++mi)                                        \
            dst[mi] = *(const bf16x8*)&Alds[(wr * 4 + mi) * 8 + kt_][l * 8];  \
    }
    // ---- B frag read (global, packed): gc0 = bx*64 + wc*4;
    // frag (nt,ni,kt) at Bbase + (((nt*8 + ni)*8 + kt) << 9)
    const unsigned short* Bbase =
        zkp + (((size_t)blockIdx.x * 64 + wc * 4) * 8) * 512 + (size_t)l * 8;
    #define LDB(dst, s_) {                                                    \
        const int nt_ = (s_) >> 3, kt_ = (s_) & 7;                            \
        _Pragma("unroll")                                                     \
        for (int ni = 0; ni < 4; ++ni)                                        \
            dst[ni] = *(const bf16x8*)(Bbase + (((nt_ * 8 + ni) * 8 + kt_) << 9)); \
    }

    bf16x8 aX[4], aY[4], bX[4], bY[4];
    LDA(aX, 0); LDB(bX, 0);           // step 0 -> X
    LDA(aY, 1); LDB(bY, 1);           // step 1 -> Y

    float partAcc[4][4] = {};

    for (int nt = 0; nt < NT; ++nt) {
        f32x4 acc[4][4] = {};

        #pragma unroll
        for (int kt = 0; kt < 8; ++kt) {
            const int s  = nt * 8 + kt;
            const int s2 = (s + 2 > NT * 8 - 1) ? (NT * 8 - 1) : (s + 2);

            if ((kt & 1) == 0) {
                __builtin_amdgcn_s_setprio(1);
                #pragma unroll
                for (int mi = 0; mi < 4; ++mi)
                    #pragma unroll
                    for (int ni = 0; ni < 4; ++ni)
                        acc[mi][ni] = __builtin_amdgcn_mfma_f32_16x16x32_bf16(
                            aX[mi], bX[ni], acc[mi][ni], 0, 0, 0);
                __builtin_amdgcn_s_setprio(0);
                LDA(aX, s2); LDB(bX, s2);          // refill X for step s+2
            } else {
                __builtin_amdgcn_s_setprio(1);
                #pragma unroll
                for (int mi = 0; mi < 4; ++mi)
                    #pragma unroll
                    for (int ni = 0; ni < 4; ++ni)
                        acc[mi][ni] = __builtin_amdgcn_mfma_f32_16x16x32_bf16(
                            aY[mi], bY[ni], acc[mi][ni], 0, 0, 0);
                __builtin_amdgcn_s_setprio(0);
                LDA(aY, s2); LDB(bY, s2);          // refill Y for step s+2
            }
        }

        // per-tile epilogue: exp + in-lane partial sums (A pre-scaled by 2)
        #pragma unroll
        for (int mi = 0; mi < 4; ++mi)
            #pragma unroll
            for (int r = 0; r < 4; ++r) {
                float s = 0.f;
                #pragma unroll
                for (int ni = 0; ni < 4; ++ni)
                    s += __expf(acc[mi][ni][r]);
                partAcc[mi][r] += s;
            }
    }
    #undef LDA
    #undef LDB

    // block epilogue: reduce across the 16 column-lanes, one atomic set
    #pragma unroll
    for (int off = 1; off <= 8; off <<= 1)
        #pragma unroll
        for (int mi = 0; mi < 4; ++mi)
            #pragma unroll
            for (int r = 0; r < 4; ++r)
                partAcc[mi][r] += __shfl_xor(partAcc[mi][r], off);

    if ((l & 15) == 0) {
        const int rg = (l >> 4) * 4;     // C/D layout: row = (l>>4)*4 + reg
        #pragma unroll
        for (int mi = 0; mi < 4; ++mi)
            #pragma unroll
            for (int r = 0; r < 4; ++r)
                atomicAdd(&rowsum[rowBase + wr * 64 + mi * 16 + rg + r],
                          partAcc[mi][r]);
    }
}

// ---------------------------------------------------------------------------
// Kernel 3: loss = mean_b [ log(exp(pos_b) + rowsum_b) - pos_b ]
// ---------------------------------------------------------------------------
__global__ __launch_bounds__(1024) void finalize_kernel(
    const float* __restrict__ pos_logit, const float* __restrict__ rowsum,
    float* __restrict__ out, int B)
{
    __shared__ float red[1024];
    float acc = 0.f;
    for (int b = (int)threadIdx.x; b < B; b += 1024) {
        const float pl = pos_logit[b];
        acc += logf(expf(pl) + rowsum[b]) - pl;
    }
    red[threadIdx.x] = acc;
    __syncthreads();
    #pragma unroll
    for (int s = 512; s; s >>= 1) {
        if ((int)threadIdx.x < s) red[threadIdx.x] += red[threadIdx.x + s];
        __syncthreads();
    }
    if (threadIdx.x == 0) out[0] = red[0] / (float)B;
}

// ---------------------------------------------------------------------------
extern "C" void kernel_launch(void* const* d_in, const int* in_sizes, int n_in,
                              void* d_out, int out_size, void* d_ws, size_t ws_size,
                              hipStream_t stream)
{
    const float* ei = (const float*)d_in[0];
    const float* ej = (const float*)d_in[1];
    const float* ek = (const float*)d_in[2];
    const int B = in_sizes[0] / D_DIM;   // 8192

    unsigned short* zip = (unsigned short*)d_ws;            // 4 MB packed A
    unsigned short* zkp = zip + (size_t)B * D_DIM;          // 4 MB packed B
    float* rowsum       = (float*)(zkp + (size_t)B * D_DIM);
    float* pos_logit    = rowsum + B;

    prep_kernel<<<dim3(B / 16), dim3(256), 0, stream>>>(
        ei, ej, ek, zip, zkp, pos_logit, rowsum);

    dim3 grid(B / (NT * BN), B / BM);    // (8, 64) = 512 blocks = 2/CU
    sim_mfma_kernel<<<grid, dim3(256), 0, stream>>>(zip, zkp, rowsum);

    finalize_kernel<<<dim3(1), dim3(1024), 0, stream>>>(
        pos_logit, rowsum, (float*)d_out, B);
}